// Round 14
// baseline (415.807 us; speedup 1.0000x reference)
//
#include <hip/hip_runtime.h>
#include <math.h>

#define BB 8
#define DSEM 256
#define DAC 36
#define DTOT 292
#define TT 4096
#define NCB 8192
#define NROWS (BB*TT)          // 32768

// output flat offsets (all float32)
static constexpr size_t O0 = 0;          // z_q (8,292,4096)
static constexpr size_t O1 = 9568256;    // sem_indices (8,4096)
static constexpr size_t O2 = 9601024;    // ac_codes (8,36,4096)
static constexpr size_t O3 = 10780672;   // vq_loss scalar
static constexpr size_t O4 = 10780673;   // z_ac_q (8,36,4096)

// MFMA-path ws layout (byte offsets). Aliases are time-disjoint (stream order):
//   Ah (dead after k_gemm)   -> wl (k_cand..k_scat)
//   Bh (dead after k_gemm)   -> result u64 (k_cand..k_out)
//   tmin (dead after k_cand) -> swl sorted worklist (k_scat/k_scan)
static constexpr size_t WB_AH   = 0;          // 16 MB f16 A'[row][k]
static constexpr size_t WB_BH   = 16777216;   //  4 MB f16 B'[j][k]
static constexpr size_t WB_TMIN = 20971520;   // 16 MB f16 tmin[row][unit]
static constexpr size_t WB_CBT  = 37748736;   //  8 MB cbT4
static constexpr size_t WB_RN   = 46137344;   // 128 KB f32 rn[row]
static constexpr size_t WB_CSQ  = 46268416;   //  32 KB f32 csq[j]
static constexpr size_t WB_LOSS = 46301184;   //   8 B double
static constexpr size_t WB_CNT  = 46301192;   //   8 B u32[2]: wl counter, loss-done
static constexpr size_t WB_HIST = 46301200;   //   1 KB u32[256] per-unit histogram
static constexpr size_t WB_CUR  = 46302224;   //   1 KB u32[256] per-unit cursor
static constexpr size_t WB_RN4  = 46303248;   //   1 MB double rn4[4][32768]
static constexpr size_t WB_END  = 47351824;
static constexpr unsigned WL_CAP = 4194304;   // worklist capacity (16MB/4B)

typedef _Float16 f16x8 __attribute__((ext_vector_type(8)));
typedef __attribute__((ext_vector_type(4))) float f32x4;

__device__ __forceinline__ void gload_lds16(const void* g, void* lds) {
  __builtin_amdgcn_global_load_lds(
      (const __attribute__((address_space(1))) void*)g,
      (__attribute__((address_space(3))) void*)lds, 16, 0, 0);
}

// ---------------- small kernels ----------------

__global__ __launch_bounds__(256) void k_fsq(const float* __restrict__ z,
                                             float* __restrict__ out) {
  int e = blockIdx.x * 256 + threadIdx.x;   // < 1179648
  int b = e / (DAC * TT);
  int rem = e - b * (DAC * TT);
  int d = rem >> 12, t = rem & 4095;
  float zv = z[((size_t)(b * DTOT + DSEM + d) << 12) + t];
  float th = (float)tanh((double)zv);
  float zb = th * 10.001f;
  float zq = rintf(zb);
  int code = (int)(zq + 10.0f);
  code = code < 0 ? 0 : (code > 20 ? 20 : code);
  out[O0 + (((size_t)(b * DTOT + DSEM + d)) << 12) + t] = zq;
  out[O2 + e] = (float)code;
  out[O4 + e] = zq;
}

// ---------------- MFMA path ----------------

// fused cb prep: Bh f16 = f16(-2c * 2^14), csq row sums, cbT4 transpose,
// init loss/counters/hist.
__global__ __launch_bounds__(256) void k_prepB2(const float* __restrict__ cb,
                                                _Float16* __restrict__ Bh,
                                                float* __restrict__ csq,
                                                float* __restrict__ cbT4,
                                                double* __restrict__ loss,
                                                unsigned* __restrict__ counters,
                                                unsigned* __restrict__ ghist) {
  if (blockIdx.x == 0) {
    if (threadIdx.x == 0) { loss[0] = 0.0; counters[0] = 0u; counters[1] = 0u; }
    ghist[threadIdx.x] = 0u;
  }
  int e = blockIdx.x * 256 + threadIdx.x;   // float4 id, < 524288
  float4 v = reinterpret_cast<const float4*>(cb)[e];
  union { _Float16 h[4]; short4 s4; } o;
  o.h[0] = (_Float16)(v.x * -32768.0f);
  o.h[1] = (_Float16)(v.y * -32768.0f);
  o.h[2] = (_Float16)(v.z * -32768.0f);
  o.h[3] = (_Float16)(v.w * -32768.0f);
  reinterpret_cast<short4*>(Bh)[e] = o.s4;
  float s = v.x * v.x + v.y * v.y + v.z * v.z + v.w * v.w;
  for (int off = 32; off; off >>= 1) s += __shfl_xor(s, off);
  if ((threadIdx.x & 63) == 0) csq[e >> 6] = s;
  // cbT4[(u*64 + k4)*32 + c] = cb[(u*32+c)*256 + k4*4 .. +3]
  int c = e & 31, r = e >> 5;
  int u = r >> 6, k4 = r & 63;
  int j = (u << 5) + c;
  float4 w = *reinterpret_cast<const float4*>(cb + (size_t)j * 256 + k4 * 4);
  reinterpret_cast<float4*>(cbT4)[e] = w;
}

// transpose z_sem -> A' f16 [row][k] + zT f32 (d_out sem region) + rn4 partials.
// R14: transposed LDS tile (pad 65), rn fused into load regs, short4/float4 stores.
// grid 2048 = b(8) x kt(4) x tt(64)
__global__ __launch_bounds__(256) void k_prepA(const float* __restrict__ z,
                                               _Float16* __restrict__ Ah,
                                               float* __restrict__ outz,
                                               double* __restrict__ rn4) {
  __shared__ float tile[64][65];   // [t2][kk]
  __shared__ double rpart[4][64];
  int bid = blockIdx.x;
  int tt = bid & 63, kt = (bid >> 6) & 3, b = bid >> 8;
  int k0 = kt * 64, t0 = tt * 64;
  int tid = threadIdx.x;
  int q = tid >> 6, t2r = tid & 63;
  double acc = 0.0;
  #pragma unroll
  for (int i = 0; i < 16; ++i) {
    int kk = i * 4 + q;
    float v = z[((size_t)(b * DTOT + k0 + kk) << 12) + t0 + t2r];
    tile[t2r][kk] = v;
    acc += (double)v * (double)v;
  }
  rpart[q][t2r] = acc;
  __syncthreads();
  float* zTb = outz + (size_t)b * (DTOT * TT);   // batch-b sem chunk: [t][k]
  #pragma unroll
  for (int i = 0; i < 4; ++i) {
    int flat = i * 256 + tid;      // < 1024
    int t2 = flat >> 4, k4g = (flat & 15) << 2;
    float f0 = tile[t2][k4g + 0], f1 = tile[t2][k4g + 1];
    float f2 = tile[t2][k4g + 2], f3 = tile[t2][k4g + 3];
    union { _Float16 h[4]; short4 s; } hh;
    hh.h[0] = (_Float16)f0; hh.h[1] = (_Float16)f1;
    hh.h[2] = (_Float16)f2; hh.h[3] = (_Float16)f3;
    *reinterpret_cast<short4*>(
        Ah + (size_t)(b * 4096 + t0 + t2) * 256 + k0 + k4g) = hh.s;
    float4 ff;
    ff.x = f0; ff.y = f1; ff.z = f2; ff.w = f3;
    *reinterpret_cast<float4*>(
        zTb + (size_t)(t0 + t2) * 256 + k0 + k4g) = ff;
  }
  if (tid < 64) {
    double s = ((rpart[0][tid] + rpart[1][tid]) + rpart[2][tid]) + rpart[3][tid];
    rn4[(size_t)kt * NROWS + (b << 12) + t0 + tid] = s;
  }
}

// coarse GEMM (R10-proven, untouched): f16 MFMA, free XOR swizzle, LDS reduce.
__global__ __launch_bounds__(256) void k_gemm(const _Float16* __restrict__ A,
                                              const _Float16* __restrict__ B,
                                              const float* __restrict__ csq,
                                              _Float16* __restrict__ tmin) {
  __shared__ char smraw[128 * 68 * 4];   // 34816 B; aliases As|Bs then red
  _Float16* As = (_Float16*)smraw;           // [128][64] (chunk-swizzled)
  _Float16* Bs = (_Float16*)(smraw + 16384); // [128][64]
  float* red = (float*)smraw;                // [128][68]
  const float SCALE = 6.103515625e-05f;      // 2^-14, exact

  int bid = blockIdx.x;
  int wg = (bid & 7) * 2048 + (bid >> 3);   // XCD swizzle (16384 % 8 == 0)
  int mtile = wg >> 6, ntile = wg & 63;
  int rbase = mtile << 7, cbase = ntile << 7;
  int tid = threadIdx.x, lane = tid & 63, wid = tid >> 6;
  int wm = wid >> 1, wn = wid & 1;
  int l15 = lane & 15, l4 = lane >> 4;
  int sw = l15 & 7;                         // == row&7 for all fragment rows

  f32x4 acc[4][4];
  #pragma unroll
  for (int mi = 0; mi < 4; ++mi)
    #pragma unroll
    for (int ni = 0; ni < 4; ++ni) acc[mi][ni] = (f32x4){0.f, 0.f, 0.f, 0.f};

  for (int kt = 0; kt < 4; ++kt) {
    int kb = kt << 6;
    __syncthreads();
    #pragma unroll
    for (int i = 0; i < 4; ++i) {
      int flat = (wid * 4 + i) * 64 + lane;   // 0..1023
      int row = flat >> 3;
      int csrc = (flat & 7) ^ (row & 7);      // inverse-swizzled global chunk
      gload_lds16(A + (size_t)(rbase + row) * 256 + kb + (csrc << 3),
                  (char*)As + flat * 16);
      gload_lds16(B + (size_t)(cbase + row) * 256 + kb + (csrc << 3),
                  (char*)Bs + flat * 16);
    }
    __syncthreads();
    #pragma unroll
    for (int ks = 0; ks < 2; ++ks) {
      int off = ((((ks << 2) + l4) ^ sw) << 3);   // one XOR for all 8 reads
      f16x8 af[4], bv[4];
      #pragma unroll
      for (int mi = 0; mi < 4; ++mi)
        af[mi] = *(const f16x8*)(As + ((wm * 64 + mi * 16 + l15) << 6) + off);
      #pragma unroll
      for (int ni = 0; ni < 4; ++ni)
        bv[ni] = *(const f16x8*)(Bs + ((wn * 64 + ni * 16 + l15) << 6) + off);
      #pragma unroll
      for (int mi = 0; mi < 4; ++mi)
        #pragma unroll
        for (int ni = 0; ni < 4; ++ni)
          acc[mi][ni] = __builtin_amdgcn_mfma_f32_16x16x32_f16(af[mi], bv[ni], acc[mi][ni], 0, 0, 0);
    }
  }

  float csv[4];
  #pragma unroll
  for (int ni = 0; ni < 4; ++ni) csv[ni] = csq[cbase + wn * 64 + ni * 16 + l15];

  __syncthreads();   // everyone done reading As/Bs before aliasing as red
  #pragma unroll
  for (int mi = 0; mi < 4; ++mi) {
    #pragma unroll
    for (int r = 0; r < 4; ++r) {
      int row = wm * 64 + mi * 16 + l4 * 4 + r;
      float v0 = fminf(fmaf(acc[mi][0][r], SCALE, csv[0]),
                       fmaf(acc[mi][1][r], SCALE, csv[1]));
      float v1 = fminf(fmaf(acc[mi][2][r], SCALE, csv[2]),
                       fmaf(acc[mi][3][r], SCALE, csv[3]));
      red[row * 68 + (wn * 2 + 0) * 16 + l15] = v0;
      red[row * 68 + (wn * 2 + 1) * 16 + l15] = v1;
    }
  }
  __syncthreads();
  if (tid < 128) {
    int row = tid;
    const float* rp = red + row * 68;
    union { _Float16 h[4]; short4 s; } uu;
    #pragma unroll
    for (int q = 0; q < 4; ++q) {
      float m = rp[q * 16];
      #pragma unroll
      for (int x = 1; x < 16; ++x) m = fminf(m, rp[q * 16 + x]);
      uu.h[q] = (_Float16)m;
    }
    *reinterpret_cast<short4*>(tmin + (size_t)(rbase + row) * 256 + ntile * 4) = uu.s;
  }
}

// per-row threshold + candidate emission + rn finalize + per-unit histogram.
__global__ __launch_bounds__(256) void k_cand(const _Float16* __restrict__ tmin,
                                              const double* __restrict__ rn4,
                                              float* __restrict__ rn,
                                              unsigned* __restrict__ wl,
                                              unsigned* __restrict__ counter,
                                              unsigned* __restrict__ ghist,
                                              unsigned long long* __restrict__ result) {
  __shared__ unsigned long long smask[16][4];
  __shared__ unsigned scnt[16];
  __shared__ unsigned soff[16];
  __shared__ unsigned lhist[256];
  int tid = threadIdx.x;
  int wv = tid >> 6, lane = tid & 63;
  int row0 = blockIdx.x << 4;
  lhist[tid] = 0u;

  for (int rr = wv; rr < 16; rr += 4) {
    int row = row0 + rr;
    const _Float16* tp = tmin + (size_t)row * 256;
    float v[4];
    #pragma unroll
    for (int i = 0; i < 4; ++i) v[i] = (float)tp[i * 64 + lane];
    float g = fminf(fminf(v[0], v[1]), fminf(v[2], v[3]));
    #pragma unroll
    for (int off = 32; off; off >>= 1) g = fminf(g, __shfl_xor(g, off));
    float thr = g + 1.5e-4f;
    if (lane == 0) {
      result[row] = 0xFFFFFFFFFFFFFFFFULL;
      double s = ((rn4[row] + rn4[NROWS + row]) + rn4[2 * NROWS + row]) +
                 rn4[3 * NROWS + row];
      rn[row] = (float)s;
    }
    unsigned cnt = 0;
    #pragma unroll
    for (int i = 0; i < 4; ++i) {
      unsigned long long mask = __ballot(v[i] <= thr);
      if (lane == 0) smask[rr][i] = mask;
      cnt += (unsigned)__popcll(mask);
    }
    if (lane == 0) scnt[rr] = cnt;
  }
  __syncthreads();
  if (tid == 0) {
    unsigned tot = 0;
    #pragma unroll
    for (int r = 0; r < 16; ++r) { soff[r] = tot; tot += scnt[r]; }
    unsigned base = atomicAdd(counter, tot);
    #pragma unroll
    for (int r = 0; r < 16; ++r) soff[r] += base;
  }
  __syncthreads();
  for (int rr = wv; rr < 16; rr += 4) {
    int row = row0 + rr;
    unsigned off = soff[rr];
    unsigned acc = 0;
    #pragma unroll
    for (int i = 0; i < 4; ++i) {
      unsigned long long mask = smask[rr][i];
      bool c = (mask >> lane) & 1ULL;
      if (c) {
        unsigned rank = acc + (unsigned)__popcll(mask & ((1ULL << lane) - 1ULL));
        unsigned idx = off + rank;
        unsigned u = (unsigned)(i * 64 + lane);
        if (idx < WL_CAP) wl[idx] = ((unsigned)row << 8) | u;
        atomicAdd(&lhist[u], 1u);
      }
      acc += (unsigned)__popcll(mask);
    }
  }
  __syncthreads();
  atomicAdd(&ghist[tid], lhist[tid]);
}

// exclusive prefix of 256-entry histogram -> cursors (1 block)
__global__ __launch_bounds__(256) void k_pref(const unsigned* __restrict__ ghist,
                                              unsigned* __restrict__ gcur) {
  __shared__ unsigned tmp[256];
  int tid = threadIdx.x;
  unsigned v = ghist[tid];
  tmp[tid] = v;
  __syncthreads();
  for (int off = 1; off < 256; off <<= 1) {
    unsigned add = (tid >= off) ? tmp[tid - off] : 0u;
    __syncthreads();
    tmp[tid] += add;
    __syncthreads();
  }
  gcur[tid] = tmp[tid] - v;   // exclusive base
}

// scatter worklist into unit-sorted order (order within bucket irrelevant:
// k_scan's atomicMin is order-independent).
__global__ __launch_bounds__(256) void k_scat(const unsigned* __restrict__ wl,
                                              const unsigned* __restrict__ counter,
                                              unsigned* __restrict__ gcur,
                                              unsigned* __restrict__ swl) {
  unsigned total = *counter;
  if (total > WL_CAP) total = WL_CAP;
  for (unsigned i = blockIdx.x * 256 + threadIdx.x; i < total;
       i += gridDim.x * 256) {
    unsigned e = wl[i];
    unsigned pos = atomicAdd(&gcur[e & 255u], 1u);
    if (pos < WL_CAP) swl[pos] = e;
  }
}

// exact scan over SORTED worklist: block takes a contiguous chunk -> its 8
// half-waves hit the same 1-2 units -> cbT4 L1/L2-hot (R14: was ~2.6 GB L2).
__global__ __launch_bounds__(256) void k_scan(const float* __restrict__ zT,
                                              const float* __restrict__ cbT4,
                                              const float* __restrict__ csq,
                                              const float* __restrict__ rn,
                                              const unsigned* __restrict__ swl,
                                              const unsigned* __restrict__ counter,
                                              unsigned long long* __restrict__ result) {
  unsigned total = *counter;
  if (total > WL_CAP) total = WL_CAP;
  unsigned C = (total + gridDim.x - 1) / gridDim.x;
  unsigned s0 = blockIdx.x * C;
  unsigned s1 = s0 + C;
  if (s1 > total) s1 = total;
  int tid = threadIdx.x;
  int sub = tid >> 5, l32 = tid & 31;
  for (unsigned it = s0 + (unsigned)sub; it < s1; it += 8u) {
    unsigned e = swl[it];
    int row = (int)(e >> 8), u = (int)(e & 255u);
    int j = (u << 5) + l32;
    int b = row >> 12, t = row & 4095;
    const float4* zp = reinterpret_cast<const float4*>(
        zT + (size_t)b * (DTOT * TT) + (size_t)t * 256);
    const float4* cp = reinterpret_cast<const float4*>(cbT4) + ((u * 64) * 32 + l32);
    float an = rn[row], cq = csq[j];
    float m0 = 0.f, m1 = 0.f, m2 = 0.f, m3 = 0.f;
    #pragma unroll 8
    for (int k4 = 0; k4 < 64; ++k4) {
      float4 cv = cp[k4 * 32];
      float4 zv = zp[k4];
      m0 = fmaf(zv.x, cv.x, m0);
      m1 = fmaf(zv.y, cv.y, m1);
      m2 = fmaf(zv.z, cv.z, m2);
      m3 = fmaf(zv.w, cv.w, m3);
    }
    float m = (m0 + m1) + (m2 + m3);
    float d = (an - 2.f * m) + cq;
    unsigned long long pk =
        (((unsigned long long)__float_as_uint(d)) << 32) | (unsigned)j;
    #pragma unroll
    for (int off = 16; off; off >>= 1) {
      unsigned long long o = __shfl_xor(pk, off);
      if (o < pk) pk = o;
    }
    if (l32 == 0) atomicMin(result + row, pk);
  }
}

// output+loss: block = (b, 32 t's) x all 256 d; half-wave per row.
__global__ __launch_bounds__(256) void k_out(const float* __restrict__ z,
                                             const float* __restrict__ cb,
                                             const unsigned long long* __restrict__ result,
                                             float* __restrict__ out0,
                                             float* __restrict__ out1,
                                             double* __restrict__ loss,
                                             unsigned* __restrict__ done,
                                             float* __restrict__ out3) {
  __shared__ float zs[32][257];   // 32896 B
  __shared__ float hsum[8];
  int bid = blockIdx.x;
  int tt = bid & 127, b = bid >> 7;
  int t0 = tt * 32;
  int tid = threadIdx.x;

  #pragma unroll
  for (int i = 0; i < 8; ++i) {
    int flat = i * 256 + tid;          // < 2048
    int d = flat >> 3, t4 = (flat & 7) * 4;
    float4 v = *reinterpret_cast<const float4*>(
        z + ((size_t)(b * DTOT + d) << 12) + t0 + t4);
    zs[t4 + 0][d] = v.x; zs[t4 + 1][d] = v.y;
    zs[t4 + 2][d] = v.z; zs[t4 + 3][d] = v.w;
  }
  __syncthreads();

  int hw = tid >> 5, l32 = tid & 31;
  float lsum = 0.f;
  #pragma unroll
  for (int p = 0; p < 4; ++p) {
    int t2 = p * 8 + hw;
    int row = (b << 12) + t0 + t2;
    unsigned j = (unsigned)(result[row] & 0xFFFFFFFFULL);
    if (l32 == 0) out1[row] = (float)j;
    const float4* cp = reinterpret_cast<const float4*>(cb + (size_t)j * 256);
    float4 c0 = cp[l32 * 2], c1 = cp[l32 * 2 + 1];
    int d0 = l32 * 8;
    float cs = 0.f, df;
    df = c0.x - zs[t2][d0 + 0]; cs = fmaf(df, df, cs); zs[t2][d0 + 0] = c0.x;
    df = c0.y - zs[t2][d0 + 1]; cs = fmaf(df, df, cs); zs[t2][d0 + 1] = c0.y;
    df = c0.z - zs[t2][d0 + 2]; cs = fmaf(df, df, cs); zs[t2][d0 + 2] = c0.z;
    df = c0.w - zs[t2][d0 + 3]; cs = fmaf(df, df, cs); zs[t2][d0 + 3] = c0.w;
    df = c1.x - zs[t2][d0 + 4]; cs = fmaf(df, df, cs); zs[t2][d0 + 4] = c1.x;
    df = c1.y - zs[t2][d0 + 5]; cs = fmaf(df, df, cs); zs[t2][d0 + 5] = c1.y;
    df = c1.z - zs[t2][d0 + 6]; cs = fmaf(df, df, cs); zs[t2][d0 + 6] = c1.z;
    df = c1.w - zs[t2][d0 + 7]; cs = fmaf(df, df, cs); zs[t2][d0 + 7] = c1.w;
    lsum += cs;
  }
  #pragma unroll
  for (int off = 16; off; off >>= 1) lsum += __shfl_xor(lsum, off);
  if (l32 == 0) hsum[hw] = lsum;
  __syncthreads();

  #pragma unroll
  for (int i = 0; i < 8; ++i) {
    int flat = i * 256 + tid;
    int d = flat >> 3, t4 = (flat & 7) * 4;
    float4 v;
    v.x = zs[t4 + 0][d]; v.y = zs[t4 + 1][d];
    v.z = zs[t4 + 2][d]; v.w = zs[t4 + 3][d];
    *reinterpret_cast<float4*>(
        out0 + ((size_t)(b * DTOT + d) << 12) + t0 + t4) = v;
  }

  if (tid == 0) {
    float tot = ((hsum[0] + hsum[1]) + (hsum[2] + hsum[3])) +
                ((hsum[4] + hsum[5]) + (hsum[6] + hsum[7]));
    atomicAdd(loss, (double)tot);
    __threadfence();
    unsigned old = atomicAdd(done, 1u);
    if (old == 1023u) {
      double total = atomicAdd(loss, 0.0);
      out3[0] = (float)(1.25 * total / 8388608.0);
    }
  }
}

// ---------------- fp32 fallback path (small-ws only) ----------------

__global__ __launch_bounds__(256) void k_csq(const float* __restrict__ cb,
                                             float* __restrict__ csq,
                                             double* __restrict__ loss,
                                             unsigned* __restrict__ counter) {
  if (blockIdx.x == 0 && threadIdx.x == 0) { loss[0] = 0.0; counter[0] = 0u; }
  int w = (blockIdx.x << 2) + (threadIdx.x >> 6);
  int lane = threadIdx.x & 63;
  float4 v = *reinterpret_cast<const float4*>(cb + (size_t)w * DSEM + lane * 4);
  float s = v.x * v.x + v.y * v.y + v.z * v.z + v.w * v.w;
  for (int off = 32; off; off >>= 1) s += __shfl_xor(s, off);
  if (lane == 0) csq[w] = s;
}

__global__ __launch_bounds__(256) void k_rn(const float* __restrict__ z,
                                            float* __restrict__ rn) {
  int r = blockIdx.x * 256 + threadIdx.x;
  int b = r >> 12, t = r & 4095;
  const float* p = z + ((size_t)(b * DTOT) << 12) + t;
  double acc = 0.0;
  #pragma unroll 8
  for (int d = 0; d < DSEM; ++d) {
    float v = p[(size_t)d << 12];
    acc += (double)v * (double)v;
  }
  rn[r] = (float)acc;
}

__global__ void k_fin(const double* __restrict__ loss, float* __restrict__ out3) {
  out3[0] = (float)(1.25 * loss[0] / 8388608.0);
}

__global__ __launch_bounds__(256) void k_vq(const float* __restrict__ z,
                                            const float* __restrict__ cb,
                                            const float* __restrict__ csq,
                                            const float* __restrict__ rn,
                                            float* __restrict__ pmin,
                                            int* __restrict__ pidx) {
  __shared__ float As[32][132];
  __shared__ float Bs[32][132];
  const int tid = threadIdx.x;
  const int tx = tid & 15, ty = tid >> 4;
  const int mb = blockIdx.x >> 2, s = blockIdx.x & 3;
  const int r0 = mb << 7;
  const int b = r0 >> 12, t0 = r0 & 4095;
  const int nbase = s * 2048;

  int mrow[8], jcol[8];
  #pragma unroll
  for (int i = 0; i < 4; ++i) {
    mrow[i] = ty * 4 + i;  mrow[i + 4] = 64 + ty * 4 + i;
    jcol[i] = tx * 4 + i;  jcol[i + 4] = 64 + tx * 4 + i;
  }
  float an[8];
  #pragma unroll
  for (int i = 0; i < 8; ++i) an[i] = rn[r0 + mrow[i]];

  float rmin[8]; int ridx[8];
  #pragma unroll
  for (int i = 0; i < 8; ++i) { rmin[i] = 3.402823466e38f; ridx[i] = 0; }

  for (int nc = 0; nc < 16; ++nc) {
    const int n0 = nbase + nc * 128;
    float acc[8][8];
    #pragma unroll
    for (int i = 0; i < 8; ++i)
      #pragma unroll
      for (int j = 0; j < 8; ++j) acc[i][j] = 0.f;

    for (int kc = 0; kc < 8; ++kc) {
      const int kb = kc << 5;
      __syncthreads();
      #pragma unroll
      for (int i = 0; i < 4; ++i) {
        int flat = i * 256 + tid;
        int k = flat >> 5, m4 = (flat & 31) << 2;
        float4 vv = *reinterpret_cast<const float4*>(
            z + ((size_t)(b * DTOT + kb + k) << 12) + t0 + m4);
        *reinterpret_cast<float4*>(&As[k][m4]) = vv;
      }
      #pragma unroll
      for (int i = 0; i < 4; ++i) {
        int flat = i * 256 + tid;
        int j = flat >> 3, k4 = (flat & 7) << 2;
        float4 vv = *reinterpret_cast<const float4*>(
            cb + ((size_t)(n0 + j) << 8) + kb + k4);
        Bs[k4 + 0][j] = vv.x; Bs[k4 + 1][j] = vv.y;
        Bs[k4 + 2][j] = vv.z; Bs[k4 + 3][j] = vv.w;
      }
      __syncthreads();
      #pragma unroll 8
      for (int k = 0; k < 32; ++k) {
        float a[8], bv[8];
        *reinterpret_cast<float4*>(&a[0]) = *reinterpret_cast<const float4*>(&As[k][ty * 4]);
        *reinterpret_cast<float4*>(&a[4]) = *reinterpret_cast<const float4*>(&As[k][64 + ty * 4]);
        *reinterpret_cast<float4*>(&bv[0]) = *reinterpret_cast<const float4*>(&Bs[k][tx * 4]);
        *reinterpret_cast<float4*>(&bv[4]) = *reinterpret_cast<const float4*>(&Bs[k][64 + tx * 4]);
        #pragma unroll
        for (int i = 0; i < 8; ++i)
          #pragma unroll
          for (int j = 0; j < 8; ++j) acc[i][j] = fmaf(a[i], bv[j], acc[i][j]);
      }
    }
    float cs[8];
    #pragma unroll
    for (int j = 0; j < 8; ++j) cs[j] = csq[n0 + jcol[j]];
    #pragma unroll
    for (int i = 0; i < 8; ++i) {
      #pragma unroll
      for (int j = 0; j < 8; ++j) {
        float d = (an[i] - 2.f * acc[i][j]) + cs[j];
        int jg = n0 + jcol[j];
        if (d < rmin[i] || (d == rmin[i] && jg < ridx[i])) { rmin[i] = d; ridx[i] = jg; }
      }
    }
  }
  __syncthreads();
  float* redf = &As[0][0];
  int* redi = reinterpret_cast<int*>(&Bs[0][0]);
  #pragma unroll
  for (int i = 0; i < 8; ++i) {
    redf[mrow[i] * 16 + tx] = rmin[i];
    redi[mrow[i] * 16 + tx] = ridx[i];
  }
  __syncthreads();
  if (tid < 128) {
    int row = tid;
    float bestv = redf[row * 16]; int bi = redi[row * 16];
    #pragma unroll
    for (int x = 1; x < 16; ++x) {
      float m = redf[row * 16 + x]; int ii = redi[row * 16 + x];
      if (m < bestv || (m == bestv && ii < bi)) { bestv = m; bi = ii; }
    }
    pmin[(size_t)(r0 + row) * 4 + s] = bestv;
    pidx[(size_t)(r0 + row) * 4 + s] = bi;
  }
}

__global__ __launch_bounds__(256) void k_comb(const float* __restrict__ pmin,
                                              const int* __restrict__ pidx,
                                              int* __restrict__ widx,
                                              float* __restrict__ out1) {
  int r = blockIdx.x * 256 + threadIdx.x;
  float best = pmin[r * 4]; int bi = pidx[r * 4];
  #pragma unroll
  for (int s2 = 1; s2 < 4; ++s2) {
    float m = pmin[r * 4 + s2]; int ii = pidx[r * 4 + s2];
    if (m < best || (m == best && ii < bi)) { best = m; bi = ii; }
  }
  widx[r] = bi;
  out1[r] = (float)bi;
}

__global__ __launch_bounds__(256) void k_loss_fb(const float* __restrict__ z,
                                                 const float* __restrict__ cb,
                                                 const int* __restrict__ idx,
                                                 float* __restrict__ out0,
                                                 double* __restrict__ loss) {
  float s = 0.f;
  for (int e = blockIdx.x * 256 + threadIdx.x; e < BB * DSEM * TT; e += 2048 * 256) {
    int b = e >> 20;
    int rem = e & 1048575;
    int d = rem >> 12, t = rem & 4095;
    int r = (b << 12) + t;
    int j = idx[r];
    float c = cb[(size_t)j * DSEM + d];
    size_t zi = ((size_t)(b * DTOT + d) << 12) + t;
    float zv = z[zi];
    out0[zi] = c;
    float df = c - zv;
    s += df * df;
  }
  for (int off = 32; off; off >>= 1) s += __shfl_xor(s, off);
  __shared__ float ws4[4];
  int lane = threadIdx.x & 63, w = threadIdx.x >> 6;
  if (lane == 0) ws4[w] = s;
  __syncthreads();
  if (threadIdx.x == 0) {
    float tot = ws4[0] + ws4[1] + ws4[2] + ws4[3];
    atomicAdd(loss, (double)tot);
  }
}

// ---------------- launch ----------------

extern "C" void kernel_launch(void* const* d_in, const int* in_sizes, int n_in,
                              void* d_out, int out_size, void* d_ws, size_t ws_size,
                              hipStream_t stream) {
  const float* z  = (const float*)d_in[0];
  const float* cb = (const float*)d_in[1];
  float* out = (float*)d_out;

  if (ws_size >= WB_END) {
    char* wsb = (char*)d_ws;
    _Float16* Ah   = (_Float16*)(wsb + WB_AH);
    _Float16* Bh   = (_Float16*)(wsb + WB_BH);
    _Float16* tmin = (_Float16*)(wsb + WB_TMIN);
    float*    cbT4 = (float*)(wsb + WB_CBT);
    float*    rn   = (float*)(wsb + WB_RN);
    float*    csq  = (float*)(wsb + WB_CSQ);
    double*   loss = (double*)(wsb + WB_LOSS);
    unsigned* counters = (unsigned*)(wsb + WB_CNT);   // [0]=wl, [1]=loss-done
    unsigned* ghist = (unsigned*)(wsb + WB_HIST);
    unsigned* gcur  = (unsigned*)(wsb + WB_CUR);
    double*   rn4  = (double*)(wsb + WB_RN4);
    unsigned* wl  = (unsigned*)(wsb + WB_AH);                      // alias (post-gemm)
    unsigned* swl = (unsigned*)(wsb + WB_TMIN);                    // alias (post-cand)
    unsigned long long* result = (unsigned long long*)(wsb + WB_BH); // alias (post-gemm)
    float* zT = out + O0;   // sem region scratch; overwritten by k_out at the end

    k_prepB2<<<2048, 256, 0, stream>>>(cb, Bh, csq, cbT4, loss, counters, ghist);
    k_fsq<<<(BB * DAC * TT) / 256, 256, 0, stream>>>(z, out);
    k_prepA<<<2048, 256, 0, stream>>>(z, Ah, zT, rn4);
    k_gemm<<<16384, 256, 0, stream>>>(Ah, Bh, csq, tmin);
    k_cand<<<NROWS / 16, 256, 0, stream>>>(tmin, rn4, rn, wl, counters, ghist, result);
    k_pref<<<1, 256, 0, stream>>>(ghist, gcur);
    k_scat<<<256, 256, 0, stream>>>(wl, counters, gcur, swl);
    k_scan<<<2048, 256, 0, stream>>>(zT, cbT4, csq, rn, swl, counters, result);
    k_out<<<1024, 256, 0, stream>>>(z, cb, result, out + O0, out + O1, loss,
                                    counters + 1, out + O3);
  } else {
    float* wsf = (float*)d_ws;
    float* csq  = wsf;
    float* rn   = wsf + 8192;
    float* pmin = wsf + 40960;
    int*   pidx = (int*)(wsf + 172032);
    int*   widx = (int*)(wsf + 303104);
    double* loss = (double*)(wsf + 335872);
    unsigned* counter = (unsigned*)(wsf + 335876);

    k_csq<<<NCB / 4, 256, 0, stream>>>(cb, csq, loss, counter);
    k_rn<<<NROWS / 256, 256, 0, stream>>>(z, rn);
    k_fsq<<<(BB * DAC * TT) / 256, 256, 0, stream>>>(z, out);
    k_vq<<<(NROWS / 128) * 4, 256, 0, stream>>>(z, cb, csq, rn, pmin, pidx);
    k_comb<<<NROWS / 256, 256, 0, stream>>>(pmin, pidx, widx, out + O1);
    k_loss_fb<<<2048, 256, 0, stream>>>(z, cb, widx, out + O0, loss);
    k_fin<<<1, 1, 0, stream>>>(loss, out + O3);
  }
}

// Round 15
// 366.132 us; speedup vs baseline: 1.1357x; 1.1357x over previous
//
#include <hip/hip_runtime.h>
#include <math.h>

#define BB 8
#define DSEM 256
#define DAC 36
#define DTOT 292
#define TT 4096
#define NCB 8192
#define NROWS (BB*TT)          // 32768

// output flat offsets (all float32)
static constexpr size_t O0 = 0;          // z_q (8,292,4096)
static constexpr size_t O1 = 9568256;    // sem_indices (8,4096)
static constexpr size_t O2 = 9601024;    // ac_codes (8,36,4096)
static constexpr size_t O3 = 10780672;   // vq_loss scalar
static constexpr size_t O4 = 10780673;   // z_ac_q (8,36,4096)

// MFMA-path ws layout (byte offsets). Aliases are time-disjoint (stream order):
//   Ah (gemm A, dead after k_gemm)  -> worklist (k_cand/k_scan)
//   Bh (gemm B, dead after k_gemm)  -> result u64 (k_cand/k_scan/k_out)
static constexpr size_t WB_AH   = 0;          // 16 MB f16 A'[row][k]
static constexpr size_t WB_BH   = 16777216;   //  4 MB f16 B'[j][k]
static constexpr size_t WB_TMIN = 20971520;   // 16 MB f16 tmin[row][unit]
static constexpr size_t WB_CBT  = 37748736;   //  8 MB cbT4
static constexpr size_t WB_RN   = 46137344;   // 128 KB f32 rn[row]
static constexpr size_t WB_CSQ  = 46268416;   //  32 KB f32 csq[j]
static constexpr size_t WB_LOSS = 46301184;   //   8 B double
static constexpr size_t WB_CNT  = 46301192;   //   8 B u32[2]: wl counter, loss-done
static constexpr size_t WB_RN4  = 46301200;   //   1 MB double rn4[4][32768]
static constexpr size_t WB_END  = 47349776;
static constexpr unsigned WL_CAP = 4194304;   // worklist capacity (16MB/4B)

typedef _Float16 f16x8 __attribute__((ext_vector_type(8)));
typedef __attribute__((ext_vector_type(4))) float f32x4;

__device__ __forceinline__ void gload_lds16(const void* g, void* lds) {
  __builtin_amdgcn_global_load_lds(
      (const __attribute__((address_space(1))) void*)g,
      (__attribute__((address_space(3))) void*)lds, 16, 0, 0);
}

// ---------------- small kernels ----------------

__global__ __launch_bounds__(256) void k_fsq(const float* __restrict__ z,
                                             float* __restrict__ out) {
  int e = blockIdx.x * 256 + threadIdx.x;   // < 1179648
  int b = e / (DAC * TT);
  int rem = e - b * (DAC * TT);
  int d = rem >> 12, t = rem & 4095;
  float zv = z[((size_t)(b * DTOT + DSEM + d) << 12) + t];
  float th = (float)tanh((double)zv);
  float zb = th * 10.001f;
  float zq = rintf(zb);
  int code = (int)(zq + 10.0f);
  code = code < 0 ? 0 : (code > 20 ? 20 : code);
  out[O0 + (((size_t)(b * DTOT + DSEM + d)) << 12) + t] = zq;
  out[O2 + e] = (float)code;
  out[O4 + e] = zq;
}

// ---------------- MFMA path ----------------

// fused cb prep: Bh f16 = f16(-2c * 2^14), csq row sums, cbT4 transpose,
// init loss/counters.
__global__ __launch_bounds__(256) void k_prepB2(const float* __restrict__ cb,
                                                _Float16* __restrict__ Bh,
                                                float* __restrict__ csq,
                                                float* __restrict__ cbT4,
                                                double* __restrict__ loss,
                                                unsigned* __restrict__ counters) {
  if (blockIdx.x == 0 && threadIdx.x == 0) {
    loss[0] = 0.0; counters[0] = 0u; counters[1] = 0u;
  }
  int e = blockIdx.x * 256 + threadIdx.x;   // float4 id, < 524288
  float4 v = reinterpret_cast<const float4*>(cb)[e];
  union { _Float16 h[4]; short4 s4; } o;
  o.h[0] = (_Float16)(v.x * -32768.0f);
  o.h[1] = (_Float16)(v.y * -32768.0f);
  o.h[2] = (_Float16)(v.z * -32768.0f);
  o.h[3] = (_Float16)(v.w * -32768.0f);
  reinterpret_cast<short4*>(Bh)[e] = o.s4;
  float s = v.x * v.x + v.y * v.y + v.z * v.z + v.w * v.w;
  for (int off = 32; off; off >>= 1) s += __shfl_xor(s, off);
  if ((threadIdx.x & 63) == 0) csq[e >> 6] = s;
  // cbT4[(u*64 + k4)*32 + c] = cb[(u*32+c)*256 + k4*4 .. +3]
  int c = e & 31, r = e >> 5;
  int u = r >> 6, k4 = r & 63;
  int j = (u << 5) + c;
  float4 w = *reinterpret_cast<const float4*>(cb + (size_t)j * 256 + k4 * 4);
  reinterpret_cast<float4*>(cbT4)[e] = w;
}

// transpose z_sem -> A' f16 [row][k] + zT f32 (d_out sem region) + rn4 partials.
// R15: vectorized (transposed LDS tile pad-65, rn fused into load regs,
// short4/float4 stores). grid 2048 = b(8) x kt(4) x tt(64)
__global__ __launch_bounds__(256) void k_prepA(const float* __restrict__ z,
                                               _Float16* __restrict__ Ah,
                                               float* __restrict__ outz,
                                               double* __restrict__ rn4) {
  __shared__ float tile[64][65];   // [t2][kk]
  __shared__ double rpart[4][64];
  int bid = blockIdx.x;
  int tt = bid & 63, kt = (bid >> 6) & 3, b = bid >> 8;
  int k0 = kt * 64, t0 = tt * 64;
  int tid = threadIdx.x;
  int q = tid >> 6, t2r = tid & 63;
  double acc = 0.0;
  #pragma unroll
  for (int i = 0; i < 16; ++i) {
    int kk = i * 4 + q;
    float v = z[((size_t)(b * DTOT + k0 + kk) << 12) + t0 + t2r];
    tile[t2r][kk] = v;
    acc += (double)v * (double)v;
  }
  rpart[q][t2r] = acc;
  __syncthreads();
  float* zTb = outz + (size_t)b * (DTOT * TT);   // batch-b sem chunk: [t][k]
  #pragma unroll
  for (int i = 0; i < 4; ++i) {
    int flat = i * 256 + tid;      // < 1024
    int t2 = flat >> 4, k4g = (flat & 15) << 2;
    float f0 = tile[t2][k4g + 0], f1 = tile[t2][k4g + 1];
    float f2 = tile[t2][k4g + 2], f3 = tile[t2][k4g + 3];
    union { _Float16 h[4]; short4 s; } hh;
    hh.h[0] = (_Float16)f0; hh.h[1] = (_Float16)f1;
    hh.h[2] = (_Float16)f2; hh.h[3] = (_Float16)f3;
    *reinterpret_cast<short4*>(
        Ah + (size_t)(b * 4096 + t0 + t2) * 256 + k0 + k4g) = hh.s;
    float4 ff;
    ff.x = f0; ff.y = f1; ff.z = f2; ff.w = f3;
    *reinterpret_cast<float4*>(
        zTb + (size_t)(t0 + t2) * 256 + k0 + k4g) = ff;
  }
  if (tid < 64) {
    double s = ((rpart[0][tid] + rpart[1][tid]) + rpart[2][tid]) + rpart[3][tid];
    rn4[(size_t)kt * NROWS + (b << 12) + t0 + tid] = s;
  }
}

// coarse GEMM (R10-proven, untouched): f16 MFMA, free XOR swizzle, LDS reduce.
__global__ __launch_bounds__(256) void k_gemm(const _Float16* __restrict__ A,
                                              const _Float16* __restrict__ B,
                                              const float* __restrict__ csq,
                                              _Float16* __restrict__ tmin) {
  __shared__ char smraw[128 * 68 * 4];   // 34816 B; aliases As|Bs then red
  _Float16* As = (_Float16*)smraw;           // [128][64] (chunk-swizzled)
  _Float16* Bs = (_Float16*)(smraw + 16384); // [128][64]
  float* red = (float*)smraw;                // [128][68]
  const float SCALE = 6.103515625e-05f;      // 2^-14, exact

  int bid = blockIdx.x;
  int wg = (bid & 7) * 2048 + (bid >> 3);   // XCD swizzle (16384 % 8 == 0)
  int mtile = wg >> 6, ntile = wg & 63;
  int rbase = mtile << 7, cbase = ntile << 7;
  int tid = threadIdx.x, lane = tid & 63, wid = tid >> 6;
  int wm = wid >> 1, wn = wid & 1;
  int l15 = lane & 15, l4 = lane >> 4;
  int sw = l15 & 7;                         // == row&7 for all fragment rows

  f32x4 acc[4][4];
  #pragma unroll
  for (int mi = 0; mi < 4; ++mi)
    #pragma unroll
    for (int ni = 0; ni < 4; ++ni) acc[mi][ni] = (f32x4){0.f, 0.f, 0.f, 0.f};

  for (int kt = 0; kt < 4; ++kt) {
    int kb = kt << 6;
    __syncthreads();
    #pragma unroll
    for (int i = 0; i < 4; ++i) {
      int flat = (wid * 4 + i) * 64 + lane;   // 0..1023
      int row = flat >> 3;
      int csrc = (flat & 7) ^ (row & 7);      // inverse-swizzled global chunk
      gload_lds16(A + (size_t)(rbase + row) * 256 + kb + (csrc << 3),
                  (char*)As + flat * 16);
      gload_lds16(B + (size_t)(cbase + row) * 256 + kb + (csrc << 3),
                  (char*)Bs + flat * 16);
    }
    __syncthreads();
    #pragma unroll
    for (int ks = 0; ks < 2; ++ks) {
      int off = ((((ks << 2) + l4) ^ sw) << 3);   // one XOR for all 8 reads
      f16x8 af[4], bv[4];
      #pragma unroll
      for (int mi = 0; mi < 4; ++mi)
        af[mi] = *(const f16x8*)(As + ((wm * 64 + mi * 16 + l15) << 6) + off);
      #pragma unroll
      for (int ni = 0; ni < 4; ++ni)
        bv[ni] = *(const f16x8*)(Bs + ((wn * 64 + ni * 16 + l15) << 6) + off);
      #pragma unroll
      for (int mi = 0; mi < 4; ++mi)
        #pragma unroll
        for (int ni = 0; ni < 4; ++ni)
          acc[mi][ni] = __builtin_amdgcn_mfma_f32_16x16x32_f16(af[mi], bv[ni], acc[mi][ni], 0, 0, 0);
    }
  }

  float csv[4];
  #pragma unroll
  for (int ni = 0; ni < 4; ++ni) csv[ni] = csq[cbase + wn * 64 + ni * 16 + l15];

  __syncthreads();   // everyone done reading As/Bs before aliasing as red
  #pragma unroll
  for (int mi = 0; mi < 4; ++mi) {
    #pragma unroll
    for (int r = 0; r < 4; ++r) {
      int row = wm * 64 + mi * 16 + l4 * 4 + r;
      float v0 = fminf(fmaf(acc[mi][0][r], SCALE, csv[0]),
                       fmaf(acc[mi][1][r], SCALE, csv[1]));
      float v1 = fminf(fmaf(acc[mi][2][r], SCALE, csv[2]),
                       fmaf(acc[mi][3][r], SCALE, csv[3]));
      red[row * 68 + (wn * 2 + 0) * 16 + l15] = v0;
      red[row * 68 + (wn * 2 + 1) * 16 + l15] = v1;
    }
  }
  __syncthreads();
  if (tid < 128) {
    int row = tid;
    const float* rp = red + row * 68;
    union { _Float16 h[4]; short4 s; } uu;
    #pragma unroll
    for (int q = 0; q < 4; ++q) {
      float m = rp[q * 16];
      #pragma unroll
      for (int x = 1; x < 16; ++x) m = fminf(m, rp[q * 16 + x]);
      uu.h[q] = (_Float16)m;
    }
    *reinterpret_cast<short4*>(tmin + (size_t)(rbase + row) * 256 + ntile * 4) = uu.s;
  }
}

// per-row threshold + candidate emission + rn finalize.
// thr = 1.5e-4 (hard bound 1.11e-4 = 2*D_f16(5e-5) + ref-quant(6.1e-5)).
__global__ __launch_bounds__(256) void k_cand(const _Float16* __restrict__ tmin,
                                              const double* __restrict__ rn4,
                                              float* __restrict__ rn,
                                              unsigned* __restrict__ wl,
                                              unsigned* __restrict__ counter,
                                              unsigned long long* __restrict__ result) {
  __shared__ unsigned long long smask[16][4];
  __shared__ unsigned scnt[16];
  __shared__ unsigned soff[16];
  int tid = threadIdx.x;
  int wv = tid >> 6, lane = tid & 63;
  int row0 = blockIdx.x << 4;

  for (int rr = wv; rr < 16; rr += 4) {
    int row = row0 + rr;
    const _Float16* tp = tmin + (size_t)row * 256;
    float v[4];
    #pragma unroll
    for (int i = 0; i < 4; ++i) v[i] = (float)tp[i * 64 + lane];
    float g = fminf(fminf(v[0], v[1]), fminf(v[2], v[3]));
    #pragma unroll
    for (int off = 32; off; off >>= 1) g = fminf(g, __shfl_xor(g, off));
    float thr = g + 1.5e-4f;
    if (lane == 0) {
      result[row] = 0xFFFFFFFFFFFFFFFFULL;
      double s = ((rn4[row] + rn4[NROWS + row]) + rn4[2 * NROWS + row]) +
                 rn4[3 * NROWS + row];
      rn[row] = (float)s;
    }
    unsigned cnt = 0;
    #pragma unroll
    for (int i = 0; i < 4; ++i) {
      unsigned long long mask = __ballot(v[i] <= thr);
      if (lane == 0) smask[rr][i] = mask;
      cnt += (unsigned)__popcll(mask);
    }
    if (lane == 0) scnt[rr] = cnt;
  }
  __syncthreads();
  if (tid == 0) {
    unsigned tot = 0;
    #pragma unroll
    for (int r = 0; r < 16; ++r) { soff[r] = tot; tot += scnt[r]; }
    unsigned base = atomicAdd(counter, tot);
    #pragma unroll
    for (int r = 0; r < 16; ++r) soff[r] += base;
  }
  __syncthreads();
  for (int rr = wv; rr < 16; rr += 4) {
    int row = row0 + rr;
    unsigned off = soff[rr];
    unsigned acc = 0;
    #pragma unroll
    for (int i = 0; i < 4; ++i) {
      unsigned long long mask = smask[rr][i];
      bool c = (mask >> lane) & 1ULL;
      if (c) {
        unsigned rank = acc + (unsigned)__popcll(mask & ((1ULL << lane) - 1ULL));
        unsigned idx = off + rank;
        if (idx < WL_CAP) wl[idx] = ((unsigned)row << 8) | (unsigned)(i * 64 + lane);
      }
      acc += (unsigned)__popcll(mask);
    }
  }
}

// exact scan: half-wave per worklist item, grid-strided.
__global__ __launch_bounds__(256) void k_scan(const float* __restrict__ zT,
                                              const float* __restrict__ cbT4,
                                              const float* __restrict__ csq,
                                              const float* __restrict__ rn,
                                              const unsigned* __restrict__ wl,
                                              const unsigned* __restrict__ counter,
                                              unsigned long long* __restrict__ result) {
  unsigned total = *counter;
  if (total > WL_CAP) total = WL_CAP;
  int tid = threadIdx.x;
  unsigned stride = gridDim.x * 8u;
  int gw = blockIdx.x * 4 + (tid >> 6);
  int half = (tid >> 5) & 1, l32 = tid & 31;
  for (unsigned it = (unsigned)(gw * 2 + half); it < total; it += stride) {
    unsigned e = wl[it];
    int row = (int)(e >> 8), u = (int)(e & 255u);
    int j = (u << 5) + l32;
    int b = row >> 12, t = row & 4095;
    const float4* zp = reinterpret_cast<const float4*>(
        zT + (size_t)b * (DTOT * TT) + (size_t)t * 256);
    const float4* cp = reinterpret_cast<const float4*>(cbT4) + ((u * 64) * 32 + l32);
    float an = rn[row], cq = csq[j];
    float m0 = 0.f, m1 = 0.f, m2 = 0.f, m3 = 0.f;
    #pragma unroll 8
    for (int k4 = 0; k4 < 64; ++k4) {
      float4 cv = cp[k4 * 32];
      float4 zv = zp[k4];
      m0 = fmaf(zv.x, cv.x, m0);
      m1 = fmaf(zv.y, cv.y, m1);
      m2 = fmaf(zv.z, cv.z, m2);
      m3 = fmaf(zv.w, cv.w, m3);
    }
    float m = (m0 + m1) + (m2 + m3);
    float d = (an - 2.f * m) + cq;
    unsigned long long pk =
        (((unsigned long long)__float_as_uint(d)) << 32) | (unsigned)j;
    #pragma unroll
    for (int off = 16; off; off >>= 1) {
      unsigned long long o = __shfl_xor(pk, off);
      if (o < pk) pk = o;
    }
    if (l32 == 0) atomicMin(result + row, pk);
  }
}

// output+loss: block = (b, 32 t's) x all 256 d; half-wave per row.
__global__ __launch_bounds__(256) void k_out(const float* __restrict__ z,
                                             const float* __restrict__ cb,
                                             const unsigned long long* __restrict__ result,
                                             float* __restrict__ out0,
                                             float* __restrict__ out1,
                                             double* __restrict__ loss,
                                             unsigned* __restrict__ done,
                                             float* __restrict__ out3) {
  __shared__ float zs[32][257];   // 32896 B
  __shared__ float hsum[8];
  int bid = blockIdx.x;
  int tt = bid & 127, b = bid >> 7;
  int t0 = tt * 32;
  int tid = threadIdx.x;

  #pragma unroll
  for (int i = 0; i < 8; ++i) {
    int flat = i * 256 + tid;          // < 2048
    int d = flat >> 3, t4 = (flat & 7) * 4;
    float4 v = *reinterpret_cast<const float4*>(
        z + ((size_t)(b * DTOT + d) << 12) + t0 + t4);
    zs[t4 + 0][d] = v.x; zs[t4 + 1][d] = v.y;
    zs[t4 + 2][d] = v.z; zs[t4 + 3][d] = v.w;
  }
  __syncthreads();

  int hw = tid >> 5, l32 = tid & 31;
  float lsum = 0.f;
  #pragma unroll
  for (int p = 0; p < 4; ++p) {
    int t2 = p * 8 + hw;
    int row = (b << 12) + t0 + t2;
    unsigned j = (unsigned)(result[row] & 0xFFFFFFFFULL);
    if (l32 == 0) out1[row] = (float)j;
    const float4* cp = reinterpret_cast<const float4*>(cb + (size_t)j * 256);
    float4 c0 = cp[l32 * 2], c1 = cp[l32 * 2 + 1];
    int d0 = l32 * 8;
    float cs = 0.f, df;
    df = c0.x - zs[t2][d0 + 0]; cs = fmaf(df, df, cs); zs[t2][d0 + 0] = c0.x;
    df = c0.y - zs[t2][d0 + 1]; cs = fmaf(df, df, cs); zs[t2][d0 + 1] = c0.y;
    df = c0.z - zs[t2][d0 + 2]; cs = fmaf(df, df, cs); zs[t2][d0 + 2] = c0.z;
    df = c0.w - zs[t2][d0 + 3]; cs = fmaf(df, df, cs); zs[t2][d0 + 3] = c0.w;
    df = c1.x - zs[t2][d0 + 4]; cs = fmaf(df, df, cs); zs[t2][d0 + 4] = c1.x;
    df = c1.y - zs[t2][d0 + 5]; cs = fmaf(df, df, cs); zs[t2][d0 + 5] = c1.y;
    df = c1.z - zs[t2][d0 + 6]; cs = fmaf(df, df, cs); zs[t2][d0 + 6] = c1.z;
    df = c1.w - zs[t2][d0 + 7]; cs = fmaf(df, df, cs); zs[t2][d0 + 7] = c1.w;
    lsum += cs;
  }
  #pragma unroll
  for (int off = 16; off; off >>= 1) lsum += __shfl_xor(lsum, off);
  if (l32 == 0) hsum[hw] = lsum;
  __syncthreads();

  #pragma unroll
  for (int i = 0; i < 8; ++i) {
    int flat = i * 256 + tid;
    int d = flat >> 3, t4 = (flat & 7) * 4;
    float4 v;
    v.x = zs[t4 + 0][d]; v.y = zs[t4 + 1][d];
    v.z = zs[t4 + 2][d]; v.w = zs[t4 + 3][d];
    *reinterpret_cast<float4*>(
        out0 + ((size_t)(b * DTOT + d) << 12) + t0 + t4) = v;
  }

  if (tid == 0) {
    float tot = ((hsum[0] + hsum[1]) + (hsum[2] + hsum[3])) +
                ((hsum[4] + hsum[5]) + (hsum[6] + hsum[7]));
    atomicAdd(loss, (double)tot);
    __threadfence();
    unsigned old = atomicAdd(done, 1u);
    if (old == 1023u) {
      double total = atomicAdd(loss, 0.0);
      out3[0] = (float)(1.25 * total / 8388608.0);
    }
  }
}

// ---------------- fp32 fallback path (small-ws only) ----------------

__global__ __launch_bounds__(256) void k_csq(const float* __restrict__ cb,
                                             float* __restrict__ csq,
                                             double* __restrict__ loss,
                                             unsigned* __restrict__ counter) {
  if (blockIdx.x == 0 && threadIdx.x == 0) { loss[0] = 0.0; counter[0] = 0u; }
  int w = (blockIdx.x << 2) + (threadIdx.x >> 6);
  int lane = threadIdx.x & 63;
  float4 v = *reinterpret_cast<const float4*>(cb + (size_t)w * DSEM + lane * 4);
  float s = v.x * v.x + v.y * v.y + v.z * v.z + v.w * v.w;
  for (int off = 32; off; off >>= 1) s += __shfl_xor(s, off);
  if (lane == 0) csq[w] = s;
}

__global__ __launch_bounds__(256) void k_rn(const float* __restrict__ z,
                                            float* __restrict__ rn) {
  int r = blockIdx.x * 256 + threadIdx.x;
  int b = r >> 12, t = r & 4095;
  const float* p = z + ((size_t)(b * DTOT) << 12) + t;
  double acc = 0.0;
  #pragma unroll 8
  for (int d = 0; d < DSEM; ++d) {
    float v = p[(size_t)d << 12];
    acc += (double)v * (double)v;
  }
  rn[r] = (float)acc;
}

__global__ void k_fin(const double* __restrict__ loss, float* __restrict__ out3) {
  out3[0] = (float)(1.25 * loss[0] / 8388608.0);
}

__global__ __launch_bounds__(256) void k_vq(const float* __restrict__ z,
                                            const float* __restrict__ cb,
                                            const float* __restrict__ csq,
                                            const float* __restrict__ rn,
                                            float* __restrict__ pmin,
                                            int* __restrict__ pidx) {
  __shared__ float As[32][132];
  __shared__ float Bs[32][132];
  const int tid = threadIdx.x;
  const int tx = tid & 15, ty = tid >> 4;
  const int mb = blockIdx.x >> 2, s = blockIdx.x & 3;
  const int r0 = mb << 7;
  const int b = r0 >> 12, t0 = r0 & 4095;
  const int nbase = s * 2048;

  int mrow[8], jcol[8];
  #pragma unroll
  for (int i = 0; i < 4; ++i) {
    mrow[i] = ty * 4 + i;  mrow[i + 4] = 64 + ty * 4 + i;
    jcol[i] = tx * 4 + i;  jcol[i + 4] = 64 + tx * 4 + i;
  }
  float an[8];
  #pragma unroll
  for (int i = 0; i < 8; ++i) an[i] = rn[r0 + mrow[i]];

  float rmin[8]; int ridx[8];
  #pragma unroll
  for (int i = 0; i < 8; ++i) { rmin[i] = 3.402823466e38f; ridx[i] = 0; }

  for (int nc = 0; nc < 16; ++nc) {
    const int n0 = nbase + nc * 128;
    float acc[8][8];
    #pragma unroll
    for (int i = 0; i < 8; ++i)
      #pragma unroll
      for (int j = 0; j < 8; ++j) acc[i][j] = 0.f;

    for (int kc = 0; kc < 8; ++kc) {
      const int kb = kc << 5;
      __syncthreads();
      #pragma unroll
      for (int i = 0; i < 4; ++i) {
        int flat = i * 256 + tid;
        int k = flat >> 5, m4 = (flat & 31) << 2;
        float4 vv = *reinterpret_cast<const float4*>(
            z + ((size_t)(b * DTOT + kb + k) << 12) + t0 + m4);
        *reinterpret_cast<float4*>(&As[k][m4]) = vv;
      }
      #pragma unroll
      for (int i = 0; i < 4; ++i) {
        int flat = i * 256 + tid;
        int j = flat >> 3, k4 = (flat & 7) << 2;
        float4 vv = *reinterpret_cast<const float4*>(
            cb + ((size_t)(n0 + j) << 8) + kb + k4);
        Bs[k4 + 0][j] = vv.x; Bs[k4 + 1][j] = vv.y;
        Bs[k4 + 2][j] = vv.z; Bs[k4 + 3][j] = vv.w;
      }
      __syncthreads();
      #pragma unroll 8
      for (int k = 0; k < 32; ++k) {
        float a[8], bv[8];
        *reinterpret_cast<float4*>(&a[0]) = *reinterpret_cast<const float4*>(&As[k][ty * 4]);
        *reinterpret_cast<float4*>(&a[4]) = *reinterpret_cast<const float4*>(&As[k][64 + ty * 4]);
        *reinterpret_cast<float4*>(&bv[0]) = *reinterpret_cast<const float4*>(&Bs[k][tx * 4]);
        *reinterpret_cast<float4*>(&bv[4]) = *reinterpret_cast<const float4*>(&Bs[k][64 + tx * 4]);
        #pragma unroll
        for (int i = 0; i < 8; ++i)
          #pragma unroll
          for (int j = 0; j < 8; ++j) acc[i][j] = fmaf(a[i], bv[j], acc[i][j]);
      }
    }
    float cs[8];
    #pragma unroll
    for (int j = 0; j < 8; ++j) cs[j] = csq[n0 + jcol[j]];
    #pragma unroll
    for (int i = 0; i < 8; ++i) {
      #pragma unroll
      for (int j = 0; j < 8; ++j) {
        float d = (an[i] - 2.f * acc[i][j]) + cs[j];
        int jg = n0 + jcol[j];
        if (d < rmin[i] || (d == rmin[i] && jg < ridx[i])) { rmin[i] = d; ridx[i] = jg; }
      }
    }
  }
  __syncthreads();
  float* redf = &As[0][0];
  int* redi = reinterpret_cast<int*>(&Bs[0][0]);
  #pragma unroll
  for (int i = 0; i < 8; ++i) {
    redf[mrow[i] * 16 + tx] = rmin[i];
    redi[mrow[i] * 16 + tx] = ridx[i];
  }
  __syncthreads();
  if (tid < 128) {
    int row = tid;
    float bestv = redf[row * 16]; int bi = redi[row * 16];
    #pragma unroll
    for (int x = 1; x < 16; ++x) {
      float m = redf[row * 16 + x]; int ii = redi[row * 16 + x];
      if (m < bestv || (m == bestv && ii < bi)) { bestv = m; bi = ii; }
    }
    pmin[(size_t)(r0 + row) * 4 + s] = bestv;
    pidx[(size_t)(r0 + row) * 4 + s] = bi;
  }
}

__global__ __launch_bounds__(256) void k_comb(const float* __restrict__ pmin,
                                              const int* __restrict__ pidx,
                                              int* __restrict__ widx,
                                              float* __restrict__ out1) {
  int r = blockIdx.x * 256 + threadIdx.x;
  float best = pmin[r * 4]; int bi = pidx[r * 4];
  #pragma unroll
  for (int s2 = 1; s2 < 4; ++s2) {
    float m = pmin[r * 4 + s2]; int ii = pidx[r * 4 + s2];
    if (m < best || (m == best && ii < bi)) { best = m; bi = ii; }
  }
  widx[r] = bi;
  out1[r] = (float)bi;
}

__global__ __launch_bounds__(256) void k_loss_fb(const float* __restrict__ z,
                                                 const float* __restrict__ cb,
                                                 const int* __restrict__ idx,
                                                 float* __restrict__ out0,
                                                 double* __restrict__ loss) {
  float s = 0.f;
  for (int e = blockIdx.x * 256 + threadIdx.x; e < BB * DSEM * TT; e += 2048 * 256) {
    int b = e >> 20;
    int rem = e & 1048575;
    int d = rem >> 12, t = rem & 4095;
    int r = (b << 12) + t;
    int j = idx[r];
    float c = cb[(size_t)j * DSEM + d];
    size_t zi = ((size_t)(b * DTOT + d) << 12) + t;
    float zv = z[zi];
    out0[zi] = c;
    float df = c - zv;
    s += df * df;
  }
  for (int off = 32; off; off >>= 1) s += __shfl_xor(s, off);
  __shared__ float ws4[4];
  int lane = threadIdx.x & 63, w = threadIdx.x >> 6;
  if (lane == 0) ws4[w] = s;
  __syncthreads();
  if (threadIdx.x == 0) {
    float tot = ws4[0] + ws4[1] + ws4[2] + ws4[3];
    atomicAdd(loss, (double)tot);
  }
}

// ---------------- launch ----------------

extern "C" void kernel_launch(void* const* d_in, const int* in_sizes, int n_in,
                              void* d_out, int out_size, void* d_ws, size_t ws_size,
                              hipStream_t stream) {
  const float* z  = (const float*)d_in[0];
  const float* cb = (const float*)d_in[1];
  float* out = (float*)d_out;

  if (ws_size >= WB_END) {
    char* wsb = (char*)d_ws;
    _Float16* Ah   = (_Float16*)(wsb + WB_AH);
    _Float16* Bh   = (_Float16*)(wsb + WB_BH);
    _Float16* tmin = (_Float16*)(wsb + WB_TMIN);
    float*    cbT4 = (float*)(wsb + WB_CBT);
    float*    rn   = (float*)(wsb + WB_RN);
    float*    csq  = (float*)(wsb + WB_CSQ);
    double*   loss = (double*)(wsb + WB_LOSS);
    unsigned* counters = (unsigned*)(wsb + WB_CNT);   // [0]=wl, [1]=loss-done
    double*   rn4  = (double*)(wsb + WB_RN4);
    unsigned* wl = (unsigned*)(wsb + WB_AH);                       // alias (post-gemm)
    unsigned long long* result = (unsigned long long*)(wsb + WB_BH); // alias (post-gemm)
    float* zT = out + O0;   // sem region scratch; overwritten by k_out at the end

    k_prepB2<<<2048, 256, 0, stream>>>(cb, Bh, csq, cbT4, loss, counters);
    k_fsq<<<(BB * DAC * TT) / 256, 256, 0, stream>>>(z, out);
    k_prepA<<<2048, 256, 0, stream>>>(z, Ah, zT, rn4);
    k_gemm<<<16384, 256, 0, stream>>>(Ah, Bh, csq, tmin);
    k_cand<<<NROWS / 16, 256, 0, stream>>>(tmin, rn4, rn, wl, counters, result);
    k_scan<<<4096, 256, 0, stream>>>(zT, cbT4, csq, rn, wl, counters, result);
    k_out<<<1024, 256, 0, stream>>>(z, cb, result, out + O0, out + O1, loss,
                                    counters + 1, out + O3);
  } else {
    float* wsf = (float*)d_ws;
    float* csq  = wsf;
    float* rn   = wsf + 8192;
    float* pmin = wsf + 40960;
    int*   pidx = (int*)(wsf + 172032);
    int*   widx = (int*)(wsf + 303104);
    double* loss = (double*)(wsf + 335872);
    unsigned* counter = (unsigned*)(wsf + 335876);

    k_csq<<<NCB / 4, 256, 0, stream>>>(cb, csq, loss, counter);
    k_rn<<<NROWS / 256, 256, 0, stream>>>(z, rn);
    k_fsq<<<(BB * DAC * TT) / 256, 256, 0, stream>>>(z, out);
    k_vq<<<(NROWS / 128) * 4, 256, 0, stream>>>(z, cb, csq, rn, pmin, pidx);
    k_comb<<<NROWS / 256, 256, 0, stream>>>(pmin, pidx, widx, out + O1);
    k_loss_fb<<<2048, 256, 0, stream>>>(z, cb, widx, out + O0, loss);
    k_fin<<<1, 1, 0, stream>>>(loss, out + O3);
  }
}